// Round 1
// baseline (2064.773 us; speedup 1.0000x reference)
//
#include <hip/hip_runtime.h>
#include <math.h>

// Problem constants (from reference):
//   x: (B=4, C=2, T=2097152) f32 ; PLAN: dsfactor=1 (no resize), bins in [128,132), tsamp=6.4e-5
//   For each bins: rows = T/bins (trunc), pad to RTOT=16384 rows, 14-stage FFA,
//   SNR = (max - median) / std(bc,ddof=1) / sqrt(16384 - added)
//   out = [periods (4*16384 f32)] ++ [snr (4,2,4*16384) f32]  -> 589824 floats
//
// Decomposition: 14 stages = 7 (pass A, within 128-row groups G) + 7 (pass B, fixed r,
// across groups G, with extra shift r<<(t-1) at sub-stage t). Both halves run fully in LDS.

#define T_LEN   2097152
#define RTOT    16384
#define STRIDE_WS  132   // ws row stride (floats)
#define STRIDE_LDS 133   // LDS row stride (odd*prime-ish -> conflict-free column access)

// ws layout (bytes):
//   [0,      32768)  : 2048 * {double sum, double sumsq} partials
//   [32768,  32800)  : 8 floats std_dev
//   [33024,  +69.2MB): y buffer, 8 * 16384 * 132 floats
#define WS_PART_OFF 0
#define WS_STD_OFF  32768
#define WS_Y_OFF    33024
#define WS_NEEDED   (33024 + (size_t)8 * RTOT * STRIDE_WS * 4)

// ---------------- std-dev (ddof=1), two-stage deterministic f64 reduction ------------
__global__ __launch_bounds__(256) void k_std_partial(const float* __restrict__ x,
                                                     double* __restrict__ part) {
  int blk = blockIdx.x;            // 2048 = 8 bc * 256 chunks
  int bc = blk >> 8, chunk = blk & 255;
  const float4* p = (const float4*)(x + (size_t)bc * T_LEN + (size_t)chunk * 8192);
  int t = threadIdx.x;
  float s = 0.f, s2 = 0.f;
#pragma unroll
  for (int kk = 0; kk < 8; ++kk) {
    float4 v = p[t + kk * 256];
    s  += v.x + v.y + v.z + v.w;
    s2 += v.x * v.x + v.y * v.y + v.z * v.z + v.w * v.w;
  }
  double ds = (double)s, ds2 = (double)s2;
  for (int off = 32; off > 0; off >>= 1) {
    ds  += __shfl_down(ds, off);
    ds2 += __shfl_down(ds2, off);
  }
  __shared__ double sm[8];
  int wid = t >> 6, lane = t & 63;
  if (lane == 0) { sm[wid] = ds; sm[wid + 4] = ds2; }
  __syncthreads();
  if (t == 0) {
    part[blk * 2]     = sm[0] + sm[1] + sm[2] + sm[3];
    part[blk * 2 + 1] = sm[4] + sm[5] + sm[6] + sm[7];
  }
}

__global__ void k_std_final(const double* __restrict__ part, float* __restrict__ stddev) {
  int t = threadIdx.x;
  if (t < 8) {
    double s = 0.0, s2 = 0.0;
    for (int i = 0; i < 256; ++i) {
      s  += part[(t * 256 + i) * 2];
      s2 += part[(t * 256 + i) * 2 + 1];
    }
    double N = (double)T_LEN;
    double var = (s2 - s * s / N) / (N - 1.0);
    stddev[t] = (float)sqrt(var);
  }
}

// ---------------- periods (np.linspace semantics, f64 then cast) ---------------------
__global__ void k_periods(float* __restrict__ out) {
  int i = blockIdx.x * 256 + threadIdx.x;   // 65536
  int bi = i >> 14, j = i & 16383;
  double tsamp = 6.4e-05;
  double p0 = tsamp * (double)(128 + bi);
  double p1 = tsamp * (double)(129 + bi);
  double step = (p1 - p0) / 16383.0;
  double v = (j == 16383) ? p1 : (p0 + (double)j * step);
  out[i] = (float)v;
}

// ---------------- shared 7-stage FFA butterfly in LDS --------------------------------
// buf0 holds input rows [0,128) x cols [0,ncol). rextra = 0 (pass A) or r (pass B).
// Returns pointer to buffer holding the result; the other buffer is free scratch.
__device__ __forceinline__ float* ffa7(float* buf0, float* buf1, int ncol, int rextra) {
  float* cur = buf0;
  float* nxt = buf1;
  int t = threadIdx.x;
  int v = t >> 1, h = t & 1;
  for (int st = 1; st <= 7; ++st) {
    __syncthreads();
    int half_g = 1 << (st - 1);
    int u = v & ((1 << st) - 1);
    int aRow = ((v >> st) << st) | (u >> 1);
    int bRow = aRow + half_g;
    int extra = (rextra << (st - 1)) % ncol;        // < ncol
    int sh = ((u + 1) >> 1) + extra;                // < 2*ncol
    if (sh >= ncol) sh -= ncol;
    const float* ca = cur + aRow * STRIDE_LDS;
    const float* cb = cur + bRow * STRIDE_LDS;
    float* nx = nxt + v * STRIDE_LDS;
    for (int j = h; j < ncol; j += 2) {
      int jj = j - sh; if (jj < 0) jj += ncol;
      nx[j] = ca[j] + cb[jj];
    }
    float* tmp = cur; cur = nxt; nxt = tmp;
  }
  __syncthreads();
  return cur;
}

// ---------------- pass A: fold from x + stages 1..7, write F7(G, r) ------------------
__global__ __launch_bounds__(256) void k_passA(const float* __restrict__ x,
                                               float* __restrict__ y,
                                               int ncol, int rows_actual) {
  extern __shared__ float lds[];
  float* buf0 = lds;
  float* buf1 = lds + 128 * STRIDE_LDS;
  int G = blockIdx.x, bc = blockIdx.y, t = threadIdx.x;

  const float* src = x + (size_t)bc * T_LEN + (size_t)G * 128 * ncol;
  int total = 128 * ncol;
  int rowlim = rows_actual - G * 128;    // rows k < rowlim are real data, rest zero-pad

  // coalesced load with incremental div by ncol
  int k = 0, c = t;
  while (c >= ncol) { c -= ncol; ++k; }
  for (int e = t; e < total; e += 256) {
    float val = 0.f;
    if (k < rowlim) val = src[e];
    buf0[k * STRIDE_LDS + c] = val;
    c += 256;
    if (c >= ncol) { c -= ncol; ++k; }
    if (c >= ncol) { c -= ncol; ++k; }
  }

  float* fin = ffa7(buf0, buf1, ncol, 0);

  // write row v -> ws row (v*128 + G); coalesced over e
  float* dst = y + (size_t)bc * RTOT * STRIDE_WS;
  k = 0; c = t;
  while (c >= ncol) { c -= ncol; ++k; }
  for (int e = t; e < total; e += 256) {
    dst[(size_t)(k * 128 + G) * STRIDE_WS + c] = fin[k * STRIDE_LDS + c];
    c += 256;
    if (c >= ncol) { c -= ncol; ++k; }
    if (c >= ncol) { c -= ncol; ++k; }
  }
}

// ---------------- pass B: stages 8..14 (extra shift r<<(t-1)) + max/median/SNR -------
__global__ __launch_bounds__(256) void k_passB(const float* __restrict__ y,
                                               const float* __restrict__ stddev,
                                               float* __restrict__ out,
                                               int ncol, int added, int bins_idx) {
  extern __shared__ float lds[];
  float* buf0 = lds;
  float* buf1 = lds + 128 * STRIDE_LDS;
  int r = blockIdx.x, bc = blockIdx.y, t = threadIdx.x;

  // contiguous 128*132 floats for this (bc, r)
  const float* src = y + ((size_t)bc * RTOT + (size_t)r * 128) * STRIDE_WS;
  int k = (t >= STRIDE_WS) ? 1 : 0;
  int c = t - k * STRIDE_WS;
  for (int e = t; e < 128 * STRIDE_WS; e += 256) {
    buf0[k * STRIDE_LDS + c] = src[e];
    c += 256;
    if (c >= STRIDE_WS) { c -= STRIDE_WS; ++k; }
    if (c >= STRIDE_WS) { c -= STRIDE_WS; ++k; }
  }

  float* fin = ffa7(buf0, buf1, ncol, r);
  float* keyb = (fin == buf0) ? buf1 : buf0;   // free scratch for sortable keys

  // SNR: row u handled by thread pair (2u, 2u+1); halves combined via shfl_xor(1)
  int u = t >> 1, h = t & 1;
  int nh = ncol >> 1;
  int jlo = h ? nh : 0;
  int jhi = h ? ncol : nh;
  const float* row = fin + u * STRIDE_LDS;
  unsigned* krow = (unsigned*)(keyb + u * STRIDE_LDS);

  float mx = -3.4e38f;
  unsigned kmin = 0xFFFFFFFFu, kmax = 0u;
  for (int j = jlo; j < jhi; ++j) {
    float f = row[j];
    mx = fmaxf(mx, f);
    unsigned ub = __float_as_uint(f);
    unsigned key = ub ^ ((ub & 0x80000000u) ? 0xFFFFFFFFu : 0x80000000u);  // order-preserving
    krow[j] = key;
    kmin = min(kmin, key);
    kmax = max(kmax, key);
  }
  mx = fmaxf(mx, __shfl_xor(mx, 1));
  {
    unsigned o = (unsigned)__shfl_xor((int)kmin, 1); kmin = min(kmin, o);
    o = (unsigned)__shfl_xor((int)kmax, 1); kmax = max(kmax, o);
  }

  // exact lower median: smallest key with count_le >= m+1 (bisection on key domain)
  int m = (ncol - 1) >> 1;
  unsigned lo = kmin, hi = kmax;
  while (lo < hi) {
    unsigned mid = lo + ((hi - lo) >> 1);
    int cnt = 0;
    for (int j = jlo; j < jhi; ++j) cnt += (krow[j] <= mid) ? 1 : 0;
    cnt += __shfl_xor(cnt, 1);
    if (cnt >= m + 1) hi = mid; else lo = mid + 1;
  }
  unsigned mk = lo;
  unsigned ub = (mk & 0x80000000u) ? (mk ^ 0x80000000u) : ~mk;
  float med = __uint_as_float(ub);

  float denom = stddev[bc] * sqrtf((float)(RTOT - added));
  float snr = (mx - med) / denom;
  if (h == 0)
    out[65536 + (size_t)bc * 65536 + (size_t)bins_idx * RTOT + r * 128 + u] = snr;
}

// ---------------- launch -------------------------------------------------------------
extern "C" void kernel_launch(void* const* d_in, const int* in_sizes, int n_in,
                              void* d_out, int out_size, void* d_ws, size_t ws_size,
                              hipStream_t stream) {
  const float* x = (const float*)d_in[0];
  float* out = (float*)d_out;
  char* ws = (char*)d_ws;
  if (ws_size < WS_NEEDED) return;  // need ~66 MB scratch

  double* part   = (double*)(ws + WS_PART_OFF);
  float*  stddev = (float*) (ws + WS_STD_OFF);
  float*  y      = (float*) (ws + WS_Y_OFF);

  // allow >64KB dynamic LDS (133 KB) — no-op if not required on ROCm
  (void)hipFuncSetAttribute((const void*)k_passA,
                            hipFuncAttributeMaxDynamicSharedMemorySize, 136192);
  (void)hipFuncSetAttribute((const void*)k_passB,
                            hipFuncAttributeMaxDynamicSharedMemorySize, 136192);

  k_std_partial<<<2048, 256, 0, stream>>>(x, part);
  k_std_final<<<1, 64, 0, stream>>>(part, stddev);
  k_periods<<<256, 256, 0, stream>>>(out);

  const int binsv[4] = {128, 129, 130, 131};
  const int rowsv[4] = {16384, 16256, 16131, 16008};
  for (int bi = 0; bi < 4; ++bi) {
    int ncol = binsv[bi];
    int added = RTOT - rowsv[bi];
    k_passA<<<dim3(128, 8), 256, 136192, stream>>>(x, y, ncol, rowsv[bi]);
    k_passB<<<dim3(128, 8), 256, 136192, stream>>>(y, stddev, out, ncol, added, bi);
  }
}

// Round 2
// 689.941 us; speedup vs baseline: 2.9927x; 2.9927x over previous
//
#include <hip/hip_runtime.h>
#include <math.h>

// FFA: x (4,2,2^21) f32, bins in {128..131}, fold -> 16384 rows -> 14-stage FFA ->
// SNR=(max-median)/std/sqrt(16384-added). out = periods(65536) ++ snr(8*65536).
//
// 14 stages = 7 in-group (pass A, 128-row groups G) + 7 cross-group (pass B, fixed r,
// extra shift r<<(t-1) per sub-stage). Both halves fully LDS-resident.
// R2: 1024 thr/block (4 waves/SIMD), register-resident median bisection, stride 136.

#define T_LEN   2097152
#define RTOT    16384
#define STRIDE_WS  132
#define STRIDE_LDS 136          // 136 % 32 == 8 -> 2-way (free) bank tiling for 8x8 wave shape
#define LDS_BYTES  (2 * 128 * STRIDE_LDS * 4)   // 139264

#define WS_PART_OFF 0
#define WS_STD_OFF  32768
#define WS_Y_OFF    33024
#define WS_NEEDED   (33024 + (size_t)8 * RTOT * STRIDE_WS * 4)

// ---------------- std-dev (ddof=1), two-stage deterministic f64 reduction ------------
__global__ __launch_bounds__(256) void k_std_partial(const float* __restrict__ x,
                                                     double* __restrict__ part) {
  int blk = blockIdx.x;            // 2048 = 8 bc * 256 chunks
  int bc = blk >> 8, chunk = blk & 255;
  const float4* p = (const float4*)(x + (size_t)bc * T_LEN + (size_t)chunk * 8192);
  int t = threadIdx.x;
  float s = 0.f, s2 = 0.f;
#pragma unroll
  for (int kk = 0; kk < 8; ++kk) {
    float4 v = p[t + kk * 256];
    s  += v.x + v.y + v.z + v.w;
    s2 += v.x * v.x + v.y * v.y + v.z * v.z + v.w * v.w;
  }
  double ds = (double)s, ds2 = (double)s2;
  for (int off = 32; off > 0; off >>= 1) {
    ds  += __shfl_down(ds, off);
    ds2 += __shfl_down(ds2, off);
  }
  __shared__ double sm[8];
  int wid = t >> 6, lane = t & 63;
  if (lane == 0) { sm[wid] = ds; sm[wid + 4] = ds2; }
  __syncthreads();
  if (t == 0) {
    part[blk * 2]     = sm[0] + sm[1] + sm[2] + sm[3];
    part[blk * 2 + 1] = sm[4] + sm[5] + sm[6] + sm[7];
  }
}

__global__ void k_std_final(const double* __restrict__ part, float* __restrict__ stddev) {
  int t = threadIdx.x;
  if (t < 8) {
    double s = 0.0, s2 = 0.0;
    for (int i = 0; i < 256; ++i) {
      s  += part[(t * 256 + i) * 2];
      s2 += part[(t * 256 + i) * 2 + 1];
    }
    double N = (double)T_LEN;
    double var = (s2 - s * s / N) / (N - 1.0);
    stddev[t] = (float)sqrt(var);
  }
}

// ---------------- periods (np.linspace semantics, f64 then cast) ---------------------
__global__ void k_periods(float* __restrict__ out) {
  int i = blockIdx.x * 256 + threadIdx.x;   // 65536
  int bi = i >> 14, j = i & 16383;
  double tsamp = 6.4e-05;
  double p0 = tsamp * (double)(128 + bi);
  double p1 = tsamp * (double)(129 + bi);
  double step = (p1 - p0) / 16383.0;
  double v = (j == 16383) ? p1 : (p0 + (double)j * step);
  out[i] = (float)v;
}

// ---------------- 7-stage FFA butterfly in LDS, 8 threads/row ------------------------
template <int NCOL>
__device__ __forceinline__ float* ffa7(float* buf0, float* buf1, int rextra) {
  float* cur = buf0;
  float* nxt = buf1;
  int t = threadIdx.x;
  int v = t >> 3, h = t & 7;          // 1024 threads = 128 rows x 8
#pragma unroll
  for (int st = 1; st <= 7; ++st) {
    __syncthreads();
    int half_g = 1 << (st - 1);
    int u = v & ((1 << st) - 1);
    int aRow = ((v >> st) << st) | (u >> 1);
    int bRow = aRow + half_g;
    int extra = (rextra << (st - 1)) % NCOL;
    int sh = ((u + 1) >> 1) + extra;
    if (sh >= NCOL) sh -= NCOL;
    const float* ca = cur + aRow * STRIDE_LDS;
    const float* cb = cur + bRow * STRIDE_LDS;
    float* nx = nxt + v * STRIDE_LDS;
#pragma unroll
    for (int i = 0; i < (NCOL + 7) / 8; ++i) {
      int j = h + 8 * i;
      if ((NCOL & 7) == 0 || j < NCOL) {
        int jj = j - sh; if (jj < 0) jj += NCOL;
        nx[j] = ca[j] + cb[jj];
      }
    }
    float* tmp = cur; cur = nxt; nxt = tmp;
  }
  __syncthreads();
  return cur;
}

// ---------------- pass A: fold from x + stages 1..7 ----------------------------------
template <int NCOL>
__global__ __launch_bounds__(1024) void k_passA(const float* __restrict__ x,
                                                float* __restrict__ y,
                                                int rows_actual) {
  extern __shared__ float lds[];
  float* buf0 = lds;
  float* buf1 = lds + 128 * STRIDE_LDS;
  int G = blockIdx.x, bc = blockIdx.y, t = threadIdx.x;

  const float* src = x + (size_t)bc * T_LEN + (size_t)G * 128 * NCOL;
  constexpr int total = 128 * NCOL;
  int rowlim = rows_actual - G * 128;    // rows k < rowlim are real data, rest zero-pad

  for (int e = t; e < total; e += 1024) {
    int k = e / NCOL, c = e % NCOL;      // compile-time NCOL -> magic mul
    float val = 0.f;
    if (k < rowlim) val = src[e];
    buf0[k * STRIDE_LDS + c] = val;
  }

  float* fin = ffa7<NCOL>(buf0, buf1, 0);

  // row v -> ws row (v*128 + G), coalesced over e
  float* dst = y + (size_t)bc * RTOT * STRIDE_WS;
  for (int e = t; e < total; e += 1024) {
    int k = e / NCOL, c = e % NCOL;
    dst[(size_t)(k * 128 + G) * STRIDE_WS + c] = fin[k * STRIDE_LDS + c];
  }
}

// ---------------- pass B: stages 8..14 + max/median/SNR ------------------------------
template <int NCOL>
__global__ __launch_bounds__(1024) void k_passB(const float* __restrict__ y,
                                                const float* __restrict__ stddev,
                                                float* __restrict__ out,
                                                int added, int bins_idx) {
  extern __shared__ float lds[];
  float* buf0 = lds;
  float* buf1 = lds + 128 * STRIDE_LDS;
  int r = blockIdx.x, bc = blockIdx.y, t = threadIdx.x;

  const float* src = y + ((size_t)bc * RTOT + (size_t)r * 128) * STRIDE_WS;
  constexpr int totalw = 128 * STRIDE_WS;
  for (int e = t; e < totalw; e += 1024) {
    int k = e / STRIDE_WS, c = e % STRIDE_WS;
    buf0[k * STRIDE_LDS + c] = src[e];
  }

  float* fin = ffa7<NCOL>(buf0, buf1, r);

  // SNR: 8 threads/row, row values held in registers (static indices)
  int u = t >> 3, h = t & 7;
  const float* row = fin + u * STRIDE_LDS;
  constexpr int NE = (NCOL + 7) / 8;
  unsigned key[NE];
  float mx = -3.4e38f;
  unsigned kmin = 0xFFFFFFFFu, kmax = 0u;
#pragma unroll
  for (int i = 0; i < NE; ++i) {
    int j = h + 8 * i;
    if ((NCOL & 7) == 0 || j < NCOL) {
      float f = row[j];
      mx = fmaxf(mx, f);
      unsigned ub = __float_as_uint(f);
      unsigned kk = ub ^ ((ub & 0x80000000u) ? 0xFFFFFFFFu : 0x80000000u);
      key[i] = kk;
      kmin = min(kmin, kk);
      kmax = max(kmax, kk);
    } else {
      key[i] = 0xFFFFFFFFu;    // sentinel: never <= mid (real-float keys < 0xFFFFFFFF)
    }
  }
  // reduce across the 8 lanes of this row (lane-aligned groups)
#pragma unroll
  for (int off = 1; off < 8; off <<= 1) {
    mx = fmaxf(mx, __shfl_xor(mx, off));
    unsigned o1 = (unsigned)__shfl_xor((int)kmin, off); kmin = min(kmin, o1);
    unsigned o2 = (unsigned)__shfl_xor((int)kmax, off); kmax = max(kmax, o2);
  }

  // exact lower median: smallest key with count_le >= m+1, bisection on key domain
  int m = (NCOL - 1) >> 1;
  unsigned lo = kmin, hi = kmax;
  while (lo < hi) {
    unsigned mid = lo + ((hi - lo) >> 1);
    int cnt = 0;
#pragma unroll
    for (int i = 0; i < NE; ++i) cnt += (key[i] <= mid) ? 1 : 0;
    cnt += __shfl_xor(cnt, 1);
    cnt += __shfl_xor(cnt, 2);
    cnt += __shfl_xor(cnt, 4);
    if (cnt >= m + 1) hi = mid; else lo = mid + 1;
  }
  unsigned mk = lo;
  unsigned ub = (mk & 0x80000000u) ? (mk ^ 0x80000000u) : ~mk;
  float med = __uint_as_float(ub);

  float denom = stddev[bc] * sqrtf((float)(RTOT - added));
  float snr = (mx - med) / denom;
  if (h == 0)
    out[65536 + (size_t)bc * 65536 + (size_t)bins_idx * RTOT + r * 128 + u] = snr;
}

// ---------------- launch -------------------------------------------------------------
extern "C" void kernel_launch(void* const* d_in, const int* in_sizes, int n_in,
                              void* d_out, int out_size, void* d_ws, size_t ws_size,
                              hipStream_t stream) {
  const float* x = (const float*)d_in[0];
  float* out = (float*)d_out;
  char* ws = (char*)d_ws;
  if (ws_size < WS_NEEDED) return;

  double* part   = (double*)(ws + WS_PART_OFF);
  float*  stddev = (float*) (ws + WS_STD_OFF);
  float*  y      = (float*) (ws + WS_Y_OFF);

  (void)hipFuncSetAttribute((const void*)k_passA<128>, hipFuncAttributeMaxDynamicSharedMemorySize, LDS_BYTES);
  (void)hipFuncSetAttribute((const void*)k_passA<129>, hipFuncAttributeMaxDynamicSharedMemorySize, LDS_BYTES);
  (void)hipFuncSetAttribute((const void*)k_passA<130>, hipFuncAttributeMaxDynamicSharedMemorySize, LDS_BYTES);
  (void)hipFuncSetAttribute((const void*)k_passA<131>, hipFuncAttributeMaxDynamicSharedMemorySize, LDS_BYTES);
  (void)hipFuncSetAttribute((const void*)k_passB<128>, hipFuncAttributeMaxDynamicSharedMemorySize, LDS_BYTES);
  (void)hipFuncSetAttribute((const void*)k_passB<129>, hipFuncAttributeMaxDynamicSharedMemorySize, LDS_BYTES);
  (void)hipFuncSetAttribute((const void*)k_passB<130>, hipFuncAttributeMaxDynamicSharedMemorySize, LDS_BYTES);
  (void)hipFuncSetAttribute((const void*)k_passB<131>, hipFuncAttributeMaxDynamicSharedMemorySize, LDS_BYTES);

  k_std_partial<<<2048, 256, 0, stream>>>(x, part);
  k_std_final<<<1, 64, 0, stream>>>(part, stddev);
  k_periods<<<256, 256, 0, stream>>>(out);

  // bins=128: rows=16384, added=0; 129: 16256; 130: 16131; 131: 16008
  k_passA<128><<<dim3(128, 8), 1024, LDS_BYTES, stream>>>(x, y, 16384);
  k_passB<128><<<dim3(128, 8), 1024, LDS_BYTES, stream>>>(y, stddev, out, 0, 0);
  k_passA<129><<<dim3(128, 8), 1024, LDS_BYTES, stream>>>(x, y, 16256);
  k_passB<129><<<dim3(128, 8), 1024, LDS_BYTES, stream>>>(y, stddev, out, 128, 1);
  k_passA<130><<<dim3(128, 8), 1024, LDS_BYTES, stream>>>(x, y, 16131);
  k_passB<130><<<dim3(128, 8), 1024, LDS_BYTES, stream>>>(y, stddev, out, 253, 2);
  k_passA<131><<<dim3(128, 8), 1024, LDS_BYTES, stream>>>(x, y, 16008);
  k_passB<131><<<dim3(128, 8), 1024, LDS_BYTES, stream>>>(y, stddev, out, 376, 3);
}

// Round 3
// 603.516 us; speedup vs baseline: 3.4212x; 1.1432x over previous
//
#include <hip/hip_runtime.h>
#include <math.h>

// FFA: x (4,2,2^21) f32, bins in {128..131}, fold -> 16384 rows -> 14-stage FFA ->
// SNR=(max-median)/std/sqrt(16384-added). out = periods(65536) ++ snr(8*65536).
//
// 14 stages = 7 in-group (pass A, 128-row groups G) + 7 cross-group (pass B, fixed r,
// extra shift r<<(t-1) per sub-stage). Both halves fully LDS-resident.
// R3: in-place single-buffer FFA (69.6 KB -> 2 blocks/CU), pair-processing with
// ds_read_b128 A-row + 5-wide scalar B window + b128 writes, float4 global staging.

#define T_LEN   2097152
#define RTOT    16384
#define STRIDE_WS  132
#define STRIDE_LDS 136          // 136 % 32 == 8 -> bank tiling; 136 % 4 == 0 -> b128 aligned
#define LDS_BYTES  (128 * STRIDE_LDS * 4)   // 69632, single buffer

#define WS_PART_OFF 0
#define WS_STD_OFF  32768
#define WS_Y_OFF    33024
#define WS_NEEDED   (33024 + (size_t)8 * RTOT * STRIDE_WS * 4)

// ---------------- std-dev (ddof=1), two-stage deterministic f64 reduction ------------
__global__ __launch_bounds__(256) void k_std_partial(const float* __restrict__ x,
                                                     double* __restrict__ part) {
  int blk = blockIdx.x;            // 2048 = 8 bc * 256 chunks
  int bc = blk >> 8, chunk = blk & 255;
  const float4* p = (const float4*)(x + (size_t)bc * T_LEN + (size_t)chunk * 8192);
  int t = threadIdx.x;
  float s = 0.f, s2 = 0.f;
#pragma unroll
  for (int kk = 0; kk < 8; ++kk) {
    float4 v = p[t + kk * 256];
    s  += v.x + v.y + v.z + v.w;
    s2 += v.x * v.x + v.y * v.y + v.z * v.z + v.w * v.w;
  }
  double ds = (double)s, ds2 = (double)s2;
  for (int off = 32; off > 0; off >>= 1) {
    ds  += __shfl_down(ds, off);
    ds2 += __shfl_down(ds2, off);
  }
  __shared__ double sm[8];
  int wid = t >> 6, lane = t & 63;
  if (lane == 0) { sm[wid] = ds; sm[wid + 4] = ds2; }
  __syncthreads();
  if (t == 0) {
    part[blk * 2]     = sm[0] + sm[1] + sm[2] + sm[3];
    part[blk * 2 + 1] = sm[4] + sm[5] + sm[6] + sm[7];
  }
}

__global__ void k_std_final(const double* __restrict__ part, float* __restrict__ stddev) {
  int t = threadIdx.x;
  if (t < 8) {
    double s = 0.0, s2 = 0.0;
    for (int i = 0; i < 256; ++i) {
      s  += part[(t * 256 + i) * 2];
      s2 += part[(t * 256 + i) * 2 + 1];
    }
    double N = (double)T_LEN;
    double var = (s2 - s * s / N) / (N - 1.0);
    stddev[t] = (float)sqrt(var);
  }
}

// ---------------- periods (np.linspace semantics, f64 then cast) ---------------------
__global__ void k_periods(float* __restrict__ out) {
  int i = blockIdx.x * 256 + threadIdx.x;   // 65536
  int bi = i >> 14, j = i & 16383;
  double tsamp = 6.4e-05;
  double p0 = tsamp * (double)(128 + bi);
  double p1 = tsamp * (double)(129 + bi);
  double step = (p1 - p0) / 16383.0;
  double v = (j == 16383) ? p1 : (p0 + (double)j * step);
  out[i] = (float)v;
}

// ---------------- 7-stage in-place FFA butterfly -------------------------------------
// buf: 128 rows x STRIDE_LDS. Cols [NCOL,132) may hold garbage: a-reads/writes touch
// them (garbage stays confined); b-reads are wrapped mod NCOL so they never do.
// Pair trick: out rows 2p,2p+1 share A-row (unshifted) and have B-shifts s, s+1:
// B window e[0..4] = bRow[(j0-s-1 .. j0-s+3) mod NCOL] serves both rows' float4.
template <int NCOL>
__device__ __forceinline__ void ffa7_inplace(float* buf, int rextra) {
  constexpr int NCHUNK = (NCOL + 3) / 4;      // 32 (NCOL=128) or 33
  constexpr int NCPT   = (NCHUNK + 15) / 16;  // 2 or 3 (3rd chunk only on hh==0)
  int t = threadIdx.x;
  int p  = t >> 4;           // pair index 0..63 -> rows 2p, 2p+1
  int hh = t & 15;
  int v0 = 2 * p;
#pragma unroll
  for (int st = 1; st <= 7; ++st) {
    __syncthreads();                      // prior stage writes (or initial load) done
    int g = 1 << st;
    int u = v0 & (g - 1);                 // even
    int aRow = ((v0 >> st) << st) | (u >> 1);
    int bRow = aRow + (g >> 1);
    int extra = (rextra << (st - 1)) % NCOL;
    int s = (u >> 1) + extra;             // shift for even row; odd row = s+1
    if (s >= NCOL) s -= NCOL;
    const float* ra = buf + aRow * STRIDE_LDS;
    const float* rb = buf + bRow * STRIDE_LDS;

    float oe[NCPT][4], oo[NCPT][4];
#pragma unroll
    for (int ci = 0; ci < NCPT; ++ci) {
      int c = hh + 16 * ci;
      bool active = (ci < 2) || (c < NCHUNK);
      if (active) {
        int j0 = c * 4;
        float4 a4 = *(const float4*)(ra + j0);
        int q0 = j0 - s - 1;
        if (q0 < 0) q0 += NCOL;           // q0 in [0, NCOL)  (j0 <= 128 < NCOL+1)
        float e[5];
#pragma unroll
        for (int k = 0; k < 5; ++k) {
          int idx = q0 + k;
          if (idx >= NCOL) idx -= NCOL;
          e[k] = rb[idx];
        }
        oe[ci][0] = a4.x + e[1]; oe[ci][1] = a4.y + e[2];
        oe[ci][2] = a4.z + e[3]; oe[ci][3] = a4.w + e[4];
        oo[ci][0] = a4.x + e[0]; oo[ci][1] = a4.y + e[1];
        oo[ci][2] = a4.z + e[2]; oo[ci][3] = a4.w + e[3];
      }
    }
    __syncthreads();                      // all reads done before in-place writes
#pragma unroll
    for (int ci = 0; ci < NCPT; ++ci) {
      int c = hh + 16 * ci;
      bool active = (ci < 2) || (c < NCHUNK);
      if (active) {
        int j0 = c * 4;
        *(float4*)(buf + (size_t)v0 * STRIDE_LDS + j0) =
            make_float4(oe[ci][0], oe[ci][1], oe[ci][2], oe[ci][3]);
        *(float4*)(buf + (size_t)(v0 + 1) * STRIDE_LDS + j0) =
            make_float4(oo[ci][0], oo[ci][1], oo[ci][2], oo[ci][3]);
      }
    }
  }
  __syncthreads();                        // final stage visible to SNR/store phase
}

// ---------------- pass A: fold from x + stages 1..7 ----------------------------------
template <int NCOL>
__global__ __launch_bounds__(1024, 8) void k_passA(const float* __restrict__ x,
                                                   float* __restrict__ y,
                                                   int rows_actual) {
  extern __shared__ float lds[];
  float* buf = lds;
  int G = blockIdx.x, bc = blockIdx.y, t = threadIdx.x;

  const float* src = x + (size_t)bc * T_LEN + (size_t)G * 128 * NCOL;
  int rowlim = rows_actual - G * 128;          // may be <=0 (fully padded group)
  int lim = rowlim * NCOL;                     // valid local element bound

  // load: linear float4 from global (aligned: 128*NCOL % 4 == 0), scalar LDS scatter
  constexpr int NF4 = 128 * NCOL / 4;
#pragma unroll
  for (int i = 0; i < (NF4 + 1023) / 1024; ++i) {
    int e4 = t + i * 1024;
    if (e4 < NF4) {
      int e = e4 * 4;
      float4 v = make_float4(0.f, 0.f, 0.f, 0.f);
      if (e + 3 < lim) {
        v = *(const float4*)(src + e);
      } else {
        float* pv = (float*)&v;
#pragma unroll
        for (int d = 0; d < 4; ++d)
          if (e + d < lim) pv[d] = src[e + d];
      }
      int k = e / NCOL, c = e % NCOL;
      const float* pv = (const float*)&v;
#pragma unroll
      for (int d = 0; d < 4; ++d) {
        buf[k * STRIDE_LDS + c] = pv[d];
        if (++c == NCOL) { c = 0; ++k; }
      }
    }
  }

  ffa7_inplace<NCOL>(buf, 0);

  // store: row v -> ws row (v*128 + G); b128 LDS read, float4 global write
  constexpr int NCH_ST = (NCOL > 128) ? 33 : 32;
  float* dst = y + (size_t)bc * RTOT * STRIDE_WS;
#pragma unroll
  for (int i = 0; i < (128 * NCH_ST + 1023) / 1024; ++i) {
    int idx = t + i * 1024;
    if (idx < 128 * NCH_ST) {
      int k = idx / NCH_ST, ch = idx % NCH_ST;
      float4 v = *(const float4*)(buf + k * STRIDE_LDS + ch * 4);
      *(float4*)(dst + ((size_t)(k * 128 + G)) * STRIDE_WS + ch * 4) = v;
    }
  }
}

// ---------------- pass B: stages 8..14 + max/median/SNR ------------------------------
template <int NCOL>
__global__ __launch_bounds__(1024, 8) void k_passB(const float* __restrict__ y,
                                                   const float* __restrict__ stddev,
                                                   float* __restrict__ out,
                                                   int added, int bins_idx) {
  extern __shared__ float lds[];
  float* buf = lds;
  int r = blockIdx.x, bc = blockIdx.y, t = threadIdx.x;

  // load: 128*132 contiguous floats = 4224 float4; float4 #idx = (row idx/33, chunk idx%33)
  const float* src = y + ((size_t)bc * RTOT + (size_t)r * 128) * STRIDE_WS;
#pragma unroll
  for (int i = 0; i < 5; ++i) {
    int idx = t + i * 1024;
    if (idx < 4224) {
      float4 v = *(const float4*)(src + idx * 4);
      int k = idx / 33, ch = idx % 33;
      *(float4*)(buf + k * STRIDE_LDS + ch * 4) = v;
    }
  }

  ffa7_inplace<NCOL>(buf, r);

  // SNR: 8 threads/row; keys loaded as b128 chunks, median via register bisection
  int u = t >> 3, h = t & 7;
  const float* row = buf + u * STRIDE_LDS;
  constexpr int NCHUNK = (NCOL + 3) / 4;
  constexpr int NCK = (NCHUNK + 7) / 8;        // chunks per thread: 4 or 5
  unsigned key[NCK * 4];
  float mx = -3.4e38f;
  unsigned kmin = 0xFFFFFFFFu, kmax = 0u;
#pragma unroll
  for (int i = 0; i < NCK; ++i) {
    int ch = h + 8 * i;
    if (ch < NCHUNK) {
      float4 v = *(const float4*)(row + ch * 4);
      const float* pv = (const float*)&v;
#pragma unroll
      for (int d = 0; d < 4; ++d) {
        int j = ch * 4 + d;
        if (j < NCOL) {
          float f = pv[d];
          mx = fmaxf(mx, f);
          unsigned ub = __float_as_uint(f);
          unsigned kk = ub ^ ((ub & 0x80000000u) ? 0xFFFFFFFFu : 0x80000000u);
          key[i * 4 + d] = kk;
          kmin = min(kmin, kk);
          kmax = max(kmax, kk);
        } else {
          key[i * 4 + d] = 0xFFFFFFFFu;        // sentinel: never <= mid
        }
      }
    } else {
#pragma unroll
      for (int d = 0; d < 4; ++d) key[i * 4 + d] = 0xFFFFFFFFu;
    }
  }
#pragma unroll
  for (int off = 1; off < 8; off <<= 1) {
    mx = fmaxf(mx, __shfl_xor(mx, off));
    unsigned o1 = (unsigned)__shfl_xor((int)kmin, off); kmin = min(kmin, o1);
    unsigned o2 = (unsigned)__shfl_xor((int)kmax, off); kmax = max(kmax, o2);
  }

  // exact lower median: smallest key with count_le >= m+1, bisection on key domain
  int m = (NCOL - 1) >> 1;
  unsigned lo = kmin, hi = kmax;
  while (lo < hi) {
    unsigned mid = lo + ((hi - lo) >> 1);
    int cnt = 0;
#pragma unroll
    for (int i = 0; i < NCK * 4; ++i) cnt += (key[i] <= mid) ? 1 : 0;
    cnt += __shfl_xor(cnt, 1);
    cnt += __shfl_xor(cnt, 2);
    cnt += __shfl_xor(cnt, 4);
    if (cnt >= m + 1) hi = mid; else lo = mid + 1;
  }
  unsigned mk = lo;
  unsigned ub = (mk & 0x80000000u) ? (mk ^ 0x80000000u) : ~mk;
  float med = __uint_as_float(ub);

  float denom = stddev[bc] * sqrtf((float)(RTOT - added));
  float snr = (mx - med) / denom;
  if (h == 0)
    out[65536 + (size_t)bc * 65536 + (size_t)bins_idx * RTOT + r * 128 + u] = snr;
}

// ---------------- launch -------------------------------------------------------------
extern "C" void kernel_launch(void* const* d_in, const int* in_sizes, int n_in,
                              void* d_out, int out_size, void* d_ws, size_t ws_size,
                              hipStream_t stream) {
  const float* x = (const float*)d_in[0];
  float* out = (float*)d_out;
  char* ws = (char*)d_ws;
  if (ws_size < WS_NEEDED) return;

  double* part   = (double*)(ws + WS_PART_OFF);
  float*  stddev = (float*) (ws + WS_STD_OFF);
  float*  y      = (float*) (ws + WS_Y_OFF);

  (void)hipFuncSetAttribute((const void*)k_passA<128>, hipFuncAttributeMaxDynamicSharedMemorySize, LDS_BYTES);
  (void)hipFuncSetAttribute((const void*)k_passA<129>, hipFuncAttributeMaxDynamicSharedMemorySize, LDS_BYTES);
  (void)hipFuncSetAttribute((const void*)k_passA<130>, hipFuncAttributeMaxDynamicSharedMemorySize, LDS_BYTES);
  (void)hipFuncSetAttribute((const void*)k_passA<131>, hipFuncAttributeMaxDynamicSharedMemorySize, LDS_BYTES);
  (void)hipFuncSetAttribute((const void*)k_passB<128>, hipFuncAttributeMaxDynamicSharedMemorySize, LDS_BYTES);
  (void)hipFuncSetAttribute((const void*)k_passB<129>, hipFuncAttributeMaxDynamicSharedMemorySize, LDS_BYTES);
  (void)hipFuncSetAttribute((const void*)k_passB<130>, hipFuncAttributeMaxDynamicSharedMemorySize, LDS_BYTES);
  (void)hipFuncSetAttribute((const void*)k_passB<131>, hipFuncAttributeMaxDynamicSharedMemorySize, LDS_BYTES);

  k_std_partial<<<2048, 256, 0, stream>>>(x, part);
  k_std_final<<<1, 64, 0, stream>>>(part, stddev);
  k_periods<<<256, 256, 0, stream>>>(out);

  // bins=128: rows=16384, added=0; 129: 16256; 130: 16131; 131: 16008
  k_passA<128><<<dim3(128, 8), 1024, LDS_BYTES, stream>>>(x, y, 16384);
  k_passB<128><<<dim3(128, 8), 1024, LDS_BYTES, stream>>>(y, stddev, out, 0, 0);
  k_passA<129><<<dim3(128, 8), 1024, LDS_BYTES, stream>>>(x, y, 16256);
  k_passB<129><<<dim3(128, 8), 1024, LDS_BYTES, stream>>>(y, stddev, out, 128, 1);
  k_passA<130><<<dim3(128, 8), 1024, LDS_BYTES, stream>>>(x, y, 16131);
  k_passB<130><<<dim3(128, 8), 1024, LDS_BYTES, stream>>>(y, stddev, out, 253, 2);
  k_passA<131><<<dim3(128, 8), 1024, LDS_BYTES, stream>>>(x, y, 16008);
  k_passB<131><<<dim3(128, 8), 1024, LDS_BYTES, stream>>>(y, stddev, out, 376, 3);
}

// Round 4
// 482.278 us; speedup vs baseline: 4.2813x; 1.2514x over previous
//
#include <hip/hip_runtime.h>
#include <math.h>

// FFA: x (4,2,2^21) f32, bins in {128..131}, fold -> 16384 rows -> 14-stage FFA ->
// SNR=(max-median)/std/sqrt(16384-added). out = periods(65536) ++ snr(8*65536).
//
// 14 stages = 7 in-group (pass A, 128-row groups G) + 7 cross-group (pass B, fixed r,
// extra shift r<<(t-1) per sub-stage). Both halves fully LDS-resident, in-place.
// R4: 4-col halo per row (no wrap math, merged B-window reads), asm-pinned register
// keys for median, fixed 16-iter unrolled bisection.

#define T_LEN   2097152
#define RTOT    16384
#define STRIDE_WS  132
#define STRIDE_LDS 136          // NCOL(<=131) + 4 halo <= 135; 136%4==0 (b128 aligned)
#define LDS_BYTES  (128 * STRIDE_LDS * 4)   // 69632, single buffer -> 2 blocks/CU

#define WS_PART_OFF 0
#define WS_STD_OFF  32768
#define WS_Y_OFF    33024
#define WS_NEEDED   (33024 + (size_t)8 * RTOT * STRIDE_WS * 4)

// ---------------- std-dev (ddof=1), two-stage deterministic f64 reduction ------------
__global__ __launch_bounds__(256) void k_std_partial(const float* __restrict__ x,
                                                     double* __restrict__ part) {
  int blk = blockIdx.x;            // 2048 = 8 bc * 256 chunks
  int bc = blk >> 8, chunk = blk & 255;
  const float4* p = (const float4*)(x + (size_t)bc * T_LEN + (size_t)chunk * 8192);
  int t = threadIdx.x;
  float s = 0.f, s2 = 0.f;
#pragma unroll
  for (int kk = 0; kk < 8; ++kk) {
    float4 v = p[t + kk * 256];
    s  += v.x + v.y + v.z + v.w;
    s2 += v.x * v.x + v.y * v.y + v.z * v.z + v.w * v.w;
  }
  double ds = (double)s, ds2 = (double)s2;
  for (int off = 32; off > 0; off >>= 1) {
    ds  += __shfl_down(ds, off);
    ds2 += __shfl_down(ds2, off);
  }
  __shared__ double sm[8];
  int wid = t >> 6, lane = t & 63;
  if (lane == 0) { sm[wid] = ds; sm[wid + 4] = ds2; }
  __syncthreads();
  if (t == 0) {
    part[blk * 2]     = sm[0] + sm[1] + sm[2] + sm[3];
    part[blk * 2 + 1] = sm[4] + sm[5] + sm[6] + sm[7];
  }
}

__global__ void k_std_final(const double* __restrict__ part, float* __restrict__ stddev) {
  int t = threadIdx.x;
  if (t < 8) {
    double s = 0.0, s2 = 0.0;
    for (int i = 0; i < 256; ++i) {
      s  += part[(t * 256 + i) * 2];
      s2 += part[(t * 256 + i) * 2 + 1];
    }
    double N = (double)T_LEN;
    double var = (s2 - s * s / N) / (N - 1.0);
    stddev[t] = (float)sqrt(var);
  }
}

// ---------------- periods (np.linspace semantics, f64 then cast) ---------------------
__global__ void k_periods(float* __restrict__ out) {
  int i = blockIdx.x * 256 + threadIdx.x;   // 65536
  int bi = i >> 14, j = i & 16383;
  double tsamp = 6.4e-05;
  double p0 = tsamp * (double)(128 + bi);
  double p1 = tsamp * (double)(129 + bi);
  double step = (p1 - p0) / 16383.0;
  double v = (j == 16383) ? p1 : (p0 + (double)j * step);
  out[i] = (float)v;
}

// ---------------- 7-stage in-place FFA butterfly with halo ---------------------------
// buf: 128 rows x STRIDE_LDS. Invariant at every stage boundary: cols [NCOL,NCOL+4)
// of each row mirror cols [0,4) (halo), so B-window reads rb[q0..q0+4], q0 in [0,NCOL),
// never wrap. Pair trick: out rows 2p,2p+1 share the A-row; shifts s, s+1; shared
// 5-float B window serves both float4 outputs.
template <int NCOL>
__device__ __forceinline__ void ffa7_inplace(float* buf, int rextra) {
  constexpr int NCHUNK = (NCOL + 3) / 4;      // 32 (NCOL=128) or 33
  constexpr int NCPT   = (NCHUNK + 15) / 16;  // 2 or 3 (3rd chunk only on hh==0)
  int t = threadIdx.x;
  int p  = t >> 4;           // pair index 0..63 -> rows 2p, 2p+1
  int hh = t & 15;
  int v0 = 2 * p;
#pragma unroll
  for (int st = 1; st <= 7; ++st) {
    __syncthreads();                      // prior stage writes (or initial load) done
    int g = 1 << st;
    int u = v0 & (g - 1);                 // even
    int aRow = ((v0 >> st) << st) | (u >> 1);
    int bRow = aRow + (g >> 1);
    int extra = (rextra << (st - 1)) % NCOL;
    int s = (u >> 1) + extra;             // shift for even row; odd row = s+1
    if (s >= NCOL) s -= NCOL;
    const float* ra = buf + aRow * STRIDE_LDS;
    const float* rb = buf + bRow * STRIDE_LDS;

    float oe[NCPT][4], oo[NCPT][4];
#pragma unroll
    for (int ci = 0; ci < NCPT; ++ci) {
      int c = hh + 16 * ci;
      bool active = (ci < 2) || (c < NCHUNK);
      if (active) {
        int j0 = c * 4;
        float4 a4 = *(const float4*)(ra + j0);
        int q0 = j0 - s - 1;
        if (q0 < 0) q0 += NCOL;           // q0 in [0, NCOL)
        const float* pb = rb + q0;        // contiguous: halo guarantees no wrap
        float e0 = pb[0], e1 = pb[1], e2 = pb[2], e3 = pb[3], e4 = pb[4];
        oe[ci][0] = a4.x + e1; oe[ci][1] = a4.y + e2;
        oe[ci][2] = a4.z + e3; oe[ci][3] = a4.w + e4;
        oo[ci][0] = a4.x + e0; oo[ci][1] = a4.y + e1;
        oo[ci][2] = a4.z + e2; oo[ci][3] = a4.w + e3;
      }
    }
    __syncthreads();                      // all reads done before in-place writes
#pragma unroll
    for (int ci = 0; ci < NCPT; ++ci) {
      int c = hh + 16 * ci;
      bool active = (ci < 2) || (c < NCHUNK);
      if (active) {
        int j0 = c * 4;
        *(float4*)(buf + (size_t)v0 * STRIDE_LDS + j0) =
            make_float4(oe[ci][0], oe[ci][1], oe[ci][2], oe[ci][3]);
        *(float4*)(buf + (size_t)(v0 + 1) * STRIDE_LDS + j0) =
            make_float4(oo[ci][0], oo[ci][1], oo[ci][2], oo[ci][3]);
      }
    }
    // halo refresh: cols [NCOL,NCOL+4) = cols [0,4). Same thread (hh==0) also wrote
    // chunk 32 (cols 128-131) when NCOL>128, so program order makes halo win.
    if (hh == 0) {
#pragma unroll
      for (int d = 0; d < 4; ++d) {
        buf[(size_t)v0 * STRIDE_LDS + NCOL + d]       = oe[0][d];
        buf[(size_t)(v0 + 1) * STRIDE_LDS + NCOL + d] = oo[0][d];
      }
    }
  }
  __syncthreads();                        // final stage visible to SNR/store phase
}

// ---------------- pass A: fold from x + stages 1..7 ----------------------------------
template <int NCOL>
__global__ __launch_bounds__(1024, 8) void k_passA(const float* __restrict__ x,
                                                   float* __restrict__ y,
                                                   int rows_actual) {
  extern __shared__ float lds[];
  float* buf = lds;
  int G = blockIdx.x, bc = blockIdx.y, t = threadIdx.x;

  const float* src = x + (size_t)bc * T_LEN + (size_t)G * 128 * NCOL;
  int rowlim = rows_actual - G * 128;
  int lim = rowlim * NCOL;

  // load: linear float4 from global, scalar LDS scatter (+halo for c<4)
  constexpr int NF4 = 128 * NCOL / 4;
#pragma unroll
  for (int i = 0; i < (NF4 + 1023) / 1024; ++i) {
    int e4 = t + i * 1024;
    if (e4 < NF4) {
      int e = e4 * 4;
      float4 v = make_float4(0.f, 0.f, 0.f, 0.f);
      if (e + 3 < lim) {
        v = *(const float4*)(src + e);
      } else {
        float* pv = (float*)&v;
#pragma unroll
        for (int d = 0; d < 4; ++d)
          if (e + d < lim) pv[d] = src[e + d];
      }
      int k = e / NCOL, c = e % NCOL;
      const float* pv = (const float*)&v;
#pragma unroll
      for (int d = 0; d < 4; ++d) {
        buf[k * STRIDE_LDS + c] = pv[d];
        if (c < 4) buf[k * STRIDE_LDS + NCOL + c] = pv[d];   // initial halo
        if (++c == NCOL) { c = 0; ++k; }
      }
    }
  }

  ffa7_inplace<NCOL>(buf, 0);

  // store: row v -> ws row (v*128 + G); b128 LDS read, float4 global write
  constexpr int NCH_ST = (NCOL > 128) ? 33 : 32;
  float* dst = y + (size_t)bc * RTOT * STRIDE_WS;
#pragma unroll
  for (int i = 0; i < (128 * NCH_ST + 1023) / 1024; ++i) {
    int idx = t + i * 1024;
    if (idx < 128 * NCH_ST) {
      int k = idx / NCH_ST, ch = idx % NCH_ST;
      float4 v = *(const float4*)(buf + k * STRIDE_LDS + ch * 4);
      *(float4*)(dst + ((size_t)(k * 128 + G)) * STRIDE_WS + ch * 4) = v;
    }
  }
}

// ---------------- pass B: stages 8..14 + max/median/SNR ------------------------------
template <int NCOL>
__global__ __launch_bounds__(1024, 8) void k_passB(const float* __restrict__ y,
                                                   const float* __restrict__ stddev,
                                                   float* __restrict__ out,
                                                   int added, int bins_idx) {
  extern __shared__ float lds[];
  float* buf = lds;
  int r = blockIdx.x, bc = blockIdx.y, t = threadIdx.x;

  // load 128*132 contiguous floats as 4224 float4. Chunk 32 holds garbage cols
  // >= NCOL: write only real cols there (halo writer owns [NCOL,NCOL+4) -- no race).
  const float* src = y + ((size_t)bc * RTOT + (size_t)r * 128) * STRIDE_WS;
#pragma unroll
  for (int i = 0; i < 5; ++i) {
    int idx = t + i * 1024;
    if (idx < 4224) {
      float4 v = *(const float4*)(src + idx * 4);
      int k = idx / 33, ch = idx % 33;
      float* drow = buf + k * STRIDE_LDS;
      const float* pv = (const float*)&v;
      if (ch == 32) {                      // cols 128..131: only NCOL-128 are real
#pragma unroll
        for (int d = 0; d < 4; ++d)
          if (128 + d < NCOL) drow[128 + d] = pv[d];
      } else {
        *(float4*)(drow + ch * 4) = v;
        if (ch == 0) {                     // initial halo = cols 0..3
#pragma unroll
          for (int d = 0; d < 4; ++d) drow[NCOL + d] = pv[d];
        }
      }
    }
  }

  ffa7_inplace<NCOL>(buf, r);

  // SNR: 8 threads/row; values -> order-preserving u32 keys pinned in VGPRs
  int u = t >> 3, h = t & 7;
  const float* row = buf + u * STRIDE_LDS;
  constexpr int NCHUNK = (NCOL + 3) / 4;
  constexpr int NCK = (NCHUNK + 7) / 8;        // float4 chunks per thread: 4 or 5
  unsigned key[NCK * 4];
  float mx = -3.4e38f;
  unsigned kmin = 0xFFFFFFFFu, kmax = 0u;
#pragma unroll
  for (int i = 0; i < NCK; ++i) {
    int ch = h + 8 * i;
    if (ch < NCHUNK) {
      float4 v = *(const float4*)(row + ch * 4);
      const float* pv = (const float*)&v;
#pragma unroll
      for (int d = 0; d < 4; ++d) {
        int j = ch * 4 + d;
        unsigned kk;
        if (j < NCOL) {                    // j>=NCOL would read halo = duplicate col
          float f = pv[d];
          mx = fmaxf(mx, f);
          unsigned ub = __float_as_uint(f);
          kk = ub ^ ((ub & 0x80000000u) ? 0xFFFFFFFFu : 0x80000000u);
          kmin = min(kmin, kk);
          kmax = max(kmax, kk);
        } else {
          kk = 0xFFFFFFFFu;                // sentinel: never <= mid (real keys smaller)
        }
        asm("" : "+v"(kk));                // pin: forbid remat-from-LDS in bisection
        key[i * 4 + d] = kk;
      }
    } else {
#pragma unroll
      for (int d = 0; d < 4; ++d) {
        unsigned kk = 0xFFFFFFFFu;
        asm("" : "+v"(kk));
        key[i * 4 + d] = kk;
      }
    }
  }
#pragma unroll
  for (int off = 1; off < 8; off <<= 1) {
    mx = fmaxf(mx, __shfl_xor(mx, off));
    unsigned o1 = (unsigned)__shfl_xor((int)kmin, off); kmin = min(kmin, o1);
    unsigned o2 = (unsigned)__shfl_xor((int)kmax, off); kmax = max(kmax, o2);
  }

  // lower median, fixed 16-iter bisection: residual <= range/2^16 (~0.03 in value,
  // ~3e-4 in SNR -- threshold is 0.109). Stable once lo==hi.
  constexpr int m = (NCOL - 1) >> 1;
  unsigned lo = kmin, hi = kmax;
#pragma unroll
  for (int it = 0; it < 16; ++it) {
    unsigned mid = lo + ((hi - lo) >> 1);
    int cnt = 0;
#pragma unroll
    for (int i = 0; i < NCK * 4; ++i) cnt += (key[i] <= mid) ? 1 : 0;
    cnt += __shfl_xor(cnt, 1);
    cnt += __shfl_xor(cnt, 2);
    cnt += __shfl_xor(cnt, 4);
    if (cnt >= m + 1) hi = mid; else lo = mid + 1;
  }
  unsigned mk = lo;
  unsigned ub = (mk & 0x80000000u) ? (mk ^ 0x80000000u) : ~mk;
  float med = __uint_as_float(ub);

  float denom = stddev[bc] * sqrtf((float)(RTOT - added));
  float snr = (mx - med) / denom;
  if (h == 0)
    out[65536 + (size_t)bc * 65536 + (size_t)bins_idx * RTOT + r * 128 + u] = snr;
}

// ---------------- launch -------------------------------------------------------------
extern "C" void kernel_launch(void* const* d_in, const int* in_sizes, int n_in,
                              void* d_out, int out_size, void* d_ws, size_t ws_size,
                              hipStream_t stream) {
  const float* x = (const float*)d_in[0];
  float* out = (float*)d_out;
  char* ws = (char*)d_ws;
  if (ws_size < WS_NEEDED) return;

  double* part   = (double*)(ws + WS_PART_OFF);
  float*  stddev = (float*) (ws + WS_STD_OFF);
  float*  y      = (float*) (ws + WS_Y_OFF);

  (void)hipFuncSetAttribute((const void*)k_passA<128>, hipFuncAttributeMaxDynamicSharedMemorySize, LDS_BYTES);
  (void)hipFuncSetAttribute((const void*)k_passA<129>, hipFuncAttributeMaxDynamicSharedMemorySize, LDS_BYTES);
  (void)hipFuncSetAttribute((const void*)k_passA<130>, hipFuncAttributeMaxDynamicSharedMemorySize, LDS_BYTES);
  (void)hipFuncSetAttribute((const void*)k_passA<131>, hipFuncAttributeMaxDynamicSharedMemorySize, LDS_BYTES);
  (void)hipFuncSetAttribute((const void*)k_passB<128>, hipFuncAttributeMaxDynamicSharedMemorySize, LDS_BYTES);
  (void)hipFuncSetAttribute((const void*)k_passB<129>, hipFuncAttributeMaxDynamicSharedMemorySize, LDS_BYTES);
  (void)hipFuncSetAttribute((const void*)k_passB<130>, hipFuncAttributeMaxDynamicSharedMemorySize, LDS_BYTES);
  (void)hipFuncSetAttribute((const void*)k_passB<131>, hipFuncAttributeMaxDynamicSharedMemorySize, LDS_BYTES);

  k_std_partial<<<2048, 256, 0, stream>>>(x, part);
  k_std_final<<<1, 64, 0, stream>>>(part, stddev);
  k_periods<<<256, 256, 0, stream>>>(out);

  // bins=128: rows=16384; 129: 16256; 130: 16131; 131: 16008
  k_passA<128><<<dim3(128, 8), 1024, LDS_BYTES, stream>>>(x, y, 16384);
  k_passB<128><<<dim3(128, 8), 1024, LDS_BYTES, stream>>>(y, stddev, out, 0, 0);
  k_passA<129><<<dim3(128, 8), 1024, LDS_BYTES, stream>>>(x, y, 16256);
  k_passB<129><<<dim3(128, 8), 1024, LDS_BYTES, stream>>>(y, stddev, out, 128, 1);
  k_passA<130><<<dim3(128, 8), 1024, LDS_BYTES, stream>>>(x, y, 16131);
  k_passB<130><<<dim3(128, 8), 1024, LDS_BYTES, stream>>>(y, stddev, out, 253, 2);
  k_passA<131><<<dim3(128, 8), 1024, LDS_BYTES, stream>>>(x, y, 16008);
  k_passB<131><<<dim3(128, 8), 1024, LDS_BYTES, stream>>>(y, stddev, out, 376, 3);
}